// Round 1
// 370.072 us; speedup vs baseline: 1.0418x; 1.0418x over previous
//
#include <hip/hip_runtime.h>

// Problem constants (fixed by the reference).
#define NN 204800
#define BB 4096
#define FF 256
#define CAP 72   // LDS-staged rows per graph, bf16 (36 KB) -> 4 blocks/CU

typedef unsigned short u16;
typedef unsigned int u32;
typedef short bf16x8 __attribute__((ext_vector_type(8)));   // 8 bf16 (4 VGPRs)
typedef float f32x4  __attribute__((ext_vector_type(4)));   // MFMA accumulator

__device__ __forceinline__ u16 rne_bf16(float f){
    union { u32 v; float f; } t; t.f = f;
    u32 lsb = (t.v >> 16) & 1u;
    t.v += 0x7fffu + lsb;
    return (u16)(t.v >> 16);
}
__device__ __forceinline__ float bf16_to_f(u16 h){
    union { u32 v; float f; } t; t.v = (u32)h << 16; return t.f;
}
__device__ __forceinline__ void cvt4(const float* __restrict__ src, u16* __restrict__ dst){
    float4 v = *(const float4*)src;
    ushort4 h;
    h.x = rne_bf16(v.x); h.y = rne_bf16(v.y);
    h.z = rne_bf16(v.z); h.w = rne_bf16(v.w);
    *(ushort4*)dst = h;
}

// K0: fused prep — segment bounds (first 4097 threads) + vectorized fp32->bf16
// conversion of g_feats, W_proj, W_ih, W_hh (4 elems/thread).
__global__ void k_prep(const float* __restrict__ gfe, const float* __restrict__ Wp,
                       const float* __restrict__ Wih, const float* __restrict__ Whh,
                       const int* __restrict__ seg, int* __restrict__ start,
                       u16* __restrict__ gfe_b, u16* __restrict__ Wp_b,
                       u16* __restrict__ Wih_b, u16* __restrict__ Whh_b){
    int i = blockIdx.x * 256 + threadIdx.x;
    if (i <= BB){
        int lo = 0, hi = NN;
        while (lo < hi){ int mid = (lo + hi) >> 1; if (seg[mid] < i) lo = mid + 1; else hi = mid; }
        start[i] = lo;
    }
    const int n_gfe = BB * FF;
    const int n_wp  = FF * FF;
    const int n_w3  = 3 * FF * FF;
    int j = i * 4;
    if (j < n_gfe){ cvt4(gfe + j, gfe_b + j); return; }
    j -= n_gfe;
    if (j < n_wp){ cvt4(Wp + j, Wp_b + j); return; }
    j -= n_wp;
    if (j < n_w3){ cvt4(Wih + j, Wih_b + j); return; }
    j -= n_w3;
    if (j < n_w3){ cvt4(Whh + j, Whh_b + j); return; }
}
#define PREP_V4 ((BB*FF + FF*FF + 2*3*FF*FF) / 4)   // 376832 threads

// K1: fused attention — ONE pass over node_feats per graph.
// Block (256 thr = 4 waves) per graph.
// Phase 0: context-logit partials for c_g (finished in Phase B; latency hides under A).
// Phase A: stream rows (4-deep unroll per wave), stage bf16 to LDS (<=CAP),
//          raw dot per node (wave-reduce), leaky+c_g deferred.
// Phase B: apply c_g+leaky during block-max pass; denom; exp weights in LDS.
// Phase C: weighted feature sum (bf16 LDS, fp32 acc) -> bf16 s.
__global__ __launch_bounds__(256) void k_attn(
        const float* __restrict__ x, const float* __restrict__ Wl,
        const float* __restrict__ bl, const float* __restrict__ gfe,
        const int* __restrict__ start, u16* __restrict__ s_b){
    __shared__ __align__(16) u16 xs[CAP][FF];    // 36 KB (bf16 staged rows)
    __shared__ float zs[512];                    // raw z, then exp weights
    __shared__ float red[16];                    // [0:4) max, [4:8) denom, [8:12) c partials
    int g = blockIdx.x;
    int s0 = start[g], cnt = start[g + 1] - s0;
    int tid = threadIdx.x, wave = tid >> 6, lane = tid & 63;
    if (cnt == 0){                   // block-uniform: safe early exit
        s_b[(size_t)g * FF + tid] = 0;
        return;
    }
    // Phase 0: c_g partial = sum_f Wl[f]*relu(gfe[g,f])  (one feature/thread)
    float p = Wl[tid] * fmaxf(gfe[(size_t)g * FF + tid], 0.f);
    #pragma unroll
    for (int o = 32; o; o >>= 1) p += __shfl_xor(p, o);
    if (lane == 0) red[8 + wave] = p;
    float blv = bl[0];
    float4 wv = *(const float4*)(Wl + FF + lane * 4);

    auto st_row = [&](int row, const float4& v){
        ushort4 h;
        h.x = rne_bf16(v.x); h.y = rne_bf16(v.y);
        h.z = rne_bf16(v.z); h.w = rne_bf16(v.w);
        *(ushort4*)(&xs[row][lane * 4]) = h;
    };

    // Phase A: 4-deep unroll (4 outstanding 1KB row loads per wave)
    int i = wave;
    for (; i + 12 < cnt; i += 16){
        const float* r0 = x + (size_t)(s0 + i) * FF + lane * 4;
        float4 xv0 = *(const float4*)(r0);
        float4 xv1 = *(const float4*)(r0 + 4 * FF);
        float4 xv2 = *(const float4*)(r0 + 8 * FF);
        float4 xv3 = *(const float4*)(r0 + 12 * FF);
        float d0 = xv0.x * wv.x + xv0.y * wv.y + xv0.z * wv.z + xv0.w * wv.w;
        float d1 = xv1.x * wv.x + xv1.y * wv.y + xv1.z * wv.z + xv1.w * wv.w;
        float d2 = xv2.x * wv.x + xv2.y * wv.y + xv2.z * wv.z + xv2.w * wv.w;
        float d3 = xv3.x * wv.x + xv3.y * wv.y + xv3.z * wv.z + xv3.w * wv.w;
        #pragma unroll
        for (int o = 32; o; o >>= 1){
            d0 += __shfl_xor(d0, o); d1 += __shfl_xor(d1, o);
            d2 += __shfl_xor(d2, o); d3 += __shfl_xor(d3, o);
        }
        if (i      < CAP) st_row(i,      xv0);
        if (i + 4  < CAP) st_row(i + 4,  xv1);
        if (i + 8  < CAP) st_row(i + 8,  xv2);
        if (i + 12 < CAP) st_row(i + 12, xv3);
        if (lane == 0){
            zs[i] = d0; zs[i + 4] = d1; zs[i + 8] = d2; zs[i + 12] = d3;
        }
    }
    for (; i < cnt; i += 4){
        float4 xv = *(const float4*)(x + (size_t)(s0 + i) * FF + lane * 4);
        float d = xv.x * wv.x + xv.y * wv.y + xv.z * wv.z + xv.w * wv.w;
        #pragma unroll
        for (int o = 32; o; o >>= 1) d += __shfl_xor(d, o);
        if (i < CAP) st_row(i, xv);
        if (lane == 0) zs[i] = d;
    }
    __syncthreads();
    // Phase B: finish c_g, apply leaky during max pass
    float cg = red[8] + red[9] + red[10] + red[11] + blv;
    float mx = -3.4e38f;
    for (int k = tid; k < cnt; k += 256){
        float t = cg + zs[k];
        t = t >= 0.f ? t : 0.01f * t;
        zs[k] = t;
        mx = fmaxf(mx, t);
    }
    #pragma unroll
    for (int o = 32; o; o >>= 1) mx = fmaxf(mx, __shfl_xor(mx, o));
    if (lane == 0) red[wave] = mx;
    __syncthreads();
    mx = fmaxf(fmaxf(red[0], red[1]), fmaxf(red[2], red[3]));
    float dsum = 0.f;
    for (int k = tid; k < cnt; k += 256){
        float e = expf(zs[k] - mx);
        zs[k] = e;
        dsum += e;
    }
    #pragma unroll
    for (int o = 32; o; o >>= 1) dsum += __shfl_xor(dsum, o);
    if (lane == 0) red[4 + wave] = dsum;
    __syncthreads();
    float inv = 1.f / (red[4] + red[5] + red[6] + red[7]);
    // Phase C: weighted sum; thread = feature
    float acc = 0.f;
    int lim = cnt < CAP ? cnt : CAP;
    for (int k = 0; k < lim; k++) acc += zs[k] * bf16_to_f(xs[k][tid]);
    for (int k = CAP; k < cnt; k++) acc += zs[k] * x[(size_t)(s0 + k) * FF + tid];
    s_b[(size_t)g * FF + tid] = rne_bf16(acc * inv);
}

// K3: MFMA proj GEMM: ctx = ELU(s @ Wp^T + gate*bp), bf16 in/out, fp32 acc.
__global__ __launch_bounds__(256) void k_proj_mfma(
        const u16* __restrict__ s_b, const u16* __restrict__ Wp_b,
        const float* __restrict__ bp, const int* __restrict__ gate,
        u16* __restrict__ ctx_b){
    int tid = threadIdx.x;
    int w = tid >> 6, l = tid & 63;
    int mn = l & 15, q = l >> 4;
    int m0 = blockIdx.x * 64 + w * 16;
    int f0 = blockIdx.y * 64;
    f32x4 acc[4] = {};
    const u16* arow = s_b + (size_t)(m0 + mn) * FF + q * 8;
    #pragma unroll
    for (int kb = 0; kb < 8; kb++){
        bf16x8 a = *(const bf16x8*)(arow + kb * 32);
        #pragma unroll
        for (int cc = 0; cc < 4; cc++){
            bf16x8 b = *(const bf16x8*)(Wp_b + (size_t)(f0 + cc * 16 + mn) * FF + kb * 32 + q * 8);
            acc[cc] = __builtin_amdgcn_mfma_f32_16x16x32_bf16(a, b, acc[cc], 0, 0, 0);
        }
    }
    #pragma unroll
    for (int cc = 0; cc < 4; cc++){
        int f = f0 + cc * 16 + mn;
        float bias = bp[f];
        #pragma unroll
        for (int r = 0; r < 4; r++){
            int g = m0 + q * 4 + r;
            float bs = (gate[g + 1] > gate[g]) ? 1.f : 0.f;
            float v = acc[cc][r] + bs * bias;
            v = v > 0.f ? v : expm1f(v);
            ctx_b[(size_t)g * FF + f] = rne_bf16(v);
        }
    }
}

// K4: MFMA fused GRU: 6 GEMM tiles (ctx@Wih_r/z/n, gfe@Whh_r/z/n) + cell epilogue.
__global__ __launch_bounds__(256) void k_gru_mfma(
        const u16* __restrict__ ctx_b, const u16* __restrict__ gfe_b,
        const u16* __restrict__ Wih_b, const u16* __restrict__ Whh_b,
        const float* __restrict__ bih, const float* __restrict__ bhh,
        const float* __restrict__ gfe, float* __restrict__ out){
    int tid = threadIdx.x;
    int w = tid >> 6, l = tid & 63;
    int mn = l & 15, q = l >> 4;
    int g0 = blockIdx.x * 64 + w * 16;
    int f0 = blockIdx.y * 64;
    f32x4 ai[3][4] = {};
    f32x4 ah[3][4] = {};
    const u16* ac_row = ctx_b + (size_t)(g0 + mn) * FF + q * 8;
    const u16* ag_row = gfe_b + (size_t)(g0 + mn) * FF + q * 8;
    #pragma unroll
    for (int kb = 0; kb < 8; kb++){
        bf16x8 a_c = *(const bf16x8*)(ac_row + kb * 32);
        bf16x8 a_g = *(const bf16x8*)(ag_row + kb * 32);
        #pragma unroll
        for (int s = 0; s < 3; s++){
            #pragma unroll
            for (int cc = 0; cc < 4; cc++){
                size_t woff = (size_t)(s * FF + f0 + cc * 16 + mn) * FF + kb * 32 + q * 8;
                bf16x8 bi = *(const bf16x8*)(Wih_b + woff);
                ai[s][cc] = __builtin_amdgcn_mfma_f32_16x16x32_bf16(a_c, bi, ai[s][cc], 0, 0, 0);
                bf16x8 bh = *(const bf16x8*)(Whh_b + woff);
                ah[s][cc] = __builtin_amdgcn_mfma_f32_16x16x32_bf16(a_g, bh, ah[s][cc], 0, 0, 0);
            }
        }
    }
    #pragma unroll
    for (int cc = 0; cc < 4; cc++){
        int f = f0 + cc * 16 + mn;
        float bir = bih[f], biz = bih[FF + f], bin_ = bih[2 * FF + f];
        float bhr = bhh[f], bhz = bhh[FF + f], bhn = bhh[2 * FF + f];
        #pragma unroll
        for (int r = 0; r < 4; r++){
            int g = g0 + q * 4 + r;
            float rg = 1.f / (1.f + expf(-(ai[0][cc][r] + bir + ah[0][cc][r] + bhr)));
            float zg = 1.f / (1.f + expf(-(ai[1][cc][r] + biz + ah[1][cc][r] + bhz)));
            float ng = tanhf(ai[2][cc][r] + bin_ + rg * (ah[2][cc][r] + bhn));
            float h = gfe[(size_t)g * FF + f];
            out[(size_t)g * FF + f] = (1.f - zg) * ng + zg * h;
        }
    }
}

extern "C" void kernel_launch(void* const* d_in, const int* in_sizes, int n_in,
                              void* d_out, int out_size, void* d_ws, size_t ws_size,
                              hipStream_t stream){
    const float* node = (const float*)d_in[0];
    const float* gfe  = (const float*)d_in[1];
    const int*   seg  = (const int*)d_in[2];
    const float* Wl   = (const float*)d_in[3];
    const float* bl   = (const float*)d_in[4];
    const float* Wp   = (const float*)d_in[5];
    const float* bp   = (const float*)d_in[6];
    const float* Wih  = (const float*)d_in[7];
    const float* Whh  = (const float*)d_in[8];
    const float* bih  = (const float*)d_in[9];
    const float* bhh  = (const float*)d_in[10];
    float* out = (float*)d_out;

    // Workspace carve-up (~7 MB total).
    char* p = (char*)d_ws;
    auto alloc = [&](size_t bytes)->void*{
        void* r = (void*)p; p += (bytes + 255) & ~(size_t)255; return r;
    };
    int*   start = (int*)  alloc((BB + 1) * sizeof(int));
    u16*   s_b   = (u16*)  alloc((size_t)BB * FF * sizeof(u16));
    u16*   ctx_b = (u16*)  alloc((size_t)BB * FF * sizeof(u16));
    u16*   gfe_b = (u16*)  alloc((size_t)BB * FF * sizeof(u16));
    u16*   Wp_b  = (u16*)  alloc((size_t)FF * FF * sizeof(u16));
    u16*   Wih_b = (u16*)  alloc((size_t)3 * FF * FF * sizeof(u16));
    u16*   Whh_b = (u16*)  alloc((size_t)3 * FF * FF * sizeof(u16));

    k_prep<<<(PREP_V4 + 255) / 256, 256, 0, stream>>>(gfe, Wp, Wih, Whh, seg, start,
                                                      gfe_b, Wp_b, Wih_b, Whh_b);
    k_attn<<<BB, 256, 0, stream>>>(node, Wl, bl, gfe, start, s_b);
    k_proj_mfma<<<dim3(BB / 64, FF / 64), 256, 0, stream>>>(s_b, Wp_b, bp, start, ctx_b);
    k_gru_mfma<<<dim3(BB / 64, FF / 64), 256, 0, stream>>>(ctx_b, gfe_b, Wih_b, Whh_b,
                                                           bih, bhh, gfe, out);
}

// Round 2
// 343.820 us; speedup vs baseline: 1.1214x; 1.0764x over previous
//
#include <hip/hip_runtime.h>

// Problem constants (fixed by the reference).
#define NN 204800
#define BB 4096
#define FF 256
#define CAP 72   // LDS-staged rows per graph, bf16 (36 KB) -> 4 blocks/CU

typedef unsigned short u16;
typedef unsigned int u32;
typedef short bf16x8 __attribute__((ext_vector_type(8)));   // 8 bf16 (4 VGPRs)
typedef float f32x4  __attribute__((ext_vector_type(4)));   // MFMA accumulator
typedef float f4     __attribute__((ext_vector_type(4)));   // for nontemporal loads

__device__ __forceinline__ u16 rne_bf16(float f){
    union { u32 v; float f; } t; t.f = f;
    u32 lsb = (t.v >> 16) & 1u;
    t.v += 0x7fffu + lsb;
    return (u16)(t.v >> 16);
}
__device__ __forceinline__ float bf16_to_f(u16 h){
    union { u32 v; float f; } t; t.v = (u32)h << 16; return t.f;
}
__device__ __forceinline__ void cvt4(const float* __restrict__ src, u16* __restrict__ dst){
    float4 v = *(const float4*)src;
    ushort4 h;
    h.x = rne_bf16(v.x); h.y = rne_bf16(v.y);
    h.z = rne_bf16(v.z); h.w = rne_bf16(v.w);
    *(ushort4*)dst = h;
}

// K0: fused prep — segment bounds (first 4097 threads) + vectorized fp32->bf16
// conversion of g_feats, W_proj, W_ih, W_hh (4 elems/thread).
__global__ void k_prep(const float* __restrict__ gfe, const float* __restrict__ Wp,
                       const float* __restrict__ Wih, const float* __restrict__ Whh,
                       const int* __restrict__ seg, int* __restrict__ start,
                       u16* __restrict__ gfe_b, u16* __restrict__ Wp_b,
                       u16* __restrict__ Wih_b, u16* __restrict__ Whh_b){
    int i = blockIdx.x * 256 + threadIdx.x;
    if (i <= BB){
        int lo = 0, hi = NN;
        while (lo < hi){ int mid = (lo + hi) >> 1; if (seg[mid] < i) lo = mid + 1; else hi = mid; }
        start[i] = lo;
    }
    const int n_gfe = BB * FF;
    const int n_wp  = FF * FF;
    const int n_w3  = 3 * FF * FF;
    int j = i * 4;
    if (j < n_gfe){ cvt4(gfe + j, gfe_b + j); return; }
    j -= n_gfe;
    if (j < n_wp){ cvt4(Wp + j, Wp_b + j); return; }
    j -= n_wp;
    if (j < n_w3){ cvt4(Wih + j, Wih_b + j); return; }
    j -= n_w3;
    if (j < n_w3){ cvt4(Whh + j, Whh_b + j); return; }
}
#define PREP_V4 ((BB*FF + FF*FF + 2*3*FF*FF) / 4)   // 376832 threads

// K1: fused attention — ONE pass over node_feats per graph (nontemporal stream).
__global__ __launch_bounds__(256) void k_attn(
        const float* __restrict__ x, const float* __restrict__ Wl,
        const float* __restrict__ bl, const float* __restrict__ gfe,
        const int* __restrict__ start, u16* __restrict__ s_b){
    __shared__ __align__(16) u16 xs[CAP][FF];    // 36 KB (bf16 staged rows)
    __shared__ float zs[512];                    // raw z, then exp weights
    __shared__ float red[16];                    // [0:4) max, [4:8) denom, [8:12) c partials
    int g = blockIdx.x;
    int s0 = start[g], cnt = start[g + 1] - s0;
    int tid = threadIdx.x, wave = tid >> 6, lane = tid & 63;
    if (cnt == 0){                   // block-uniform: safe early exit
        s_b[(size_t)g * FF + tid] = 0;
        return;
    }
    // Phase 0: c_g partial = sum_f Wl[f]*relu(gfe[g,f])  (one feature/thread)
    float p = Wl[tid] * fmaxf(gfe[(size_t)g * FF + tid], 0.f);
    #pragma unroll
    for (int o = 32; o; o >>= 1) p += __shfl_xor(p, o);
    if (lane == 0) red[8 + wave] = p;
    float blv = bl[0];
    f4 wv = *(const f4*)(Wl + FF + lane * 4);

    auto st_row = [&](int row, const f4& v){
        ushort4 h;
        h.x = rne_bf16(v.x); h.y = rne_bf16(v.y);
        h.z = rne_bf16(v.z); h.w = rne_bf16(v.w);
        *(ushort4*)(&xs[row][lane * 4]) = h;
    };

    // Phase A: 4-deep unroll (4 outstanding 1KB row loads per wave), nontemporal
    int i = wave;
    for (; i + 12 < cnt; i += 16){
        const f4* r0 = (const f4*)(x + (size_t)(s0 + i) * FF + lane * 4);
        f4 xv0 = __builtin_nontemporal_load(r0);
        f4 xv1 = __builtin_nontemporal_load(r0 + FF);        // +4 rows (4*FF floats)
        f4 xv2 = __builtin_nontemporal_load(r0 + 2 * FF);
        f4 xv3 = __builtin_nontemporal_load(r0 + 3 * FF);
        float d0 = xv0.x * wv.x + xv0.y * wv.y + xv0.z * wv.z + xv0.w * wv.w;
        float d1 = xv1.x * wv.x + xv1.y * wv.y + xv1.z * wv.z + xv1.w * wv.w;
        float d2 = xv2.x * wv.x + xv2.y * wv.y + xv2.z * wv.z + xv2.w * wv.w;
        float d3 = xv3.x * wv.x + xv3.y * wv.y + xv3.z * wv.z + xv3.w * wv.w;
        #pragma unroll
        for (int o = 32; o; o >>= 1){
            d0 += __shfl_xor(d0, o); d1 += __shfl_xor(d1, o);
            d2 += __shfl_xor(d2, o); d3 += __shfl_xor(d3, o);
        }
        if (i      < CAP) st_row(i,      xv0);
        if (i + 4  < CAP) st_row(i + 4,  xv1);
        if (i + 8  < CAP) st_row(i + 8,  xv2);
        if (i + 12 < CAP) st_row(i + 12, xv3);
        if (lane == 0){
            zs[i] = d0; zs[i + 4] = d1; zs[i + 8] = d2; zs[i + 12] = d3;
        }
    }
    for (; i < cnt; i += 4){
        f4 xv = *(const f4*)(x + (size_t)(s0 + i) * FF + lane * 4);
        float d = xv.x * wv.x + xv.y * wv.y + xv.z * wv.z + xv.w * wv.w;
        #pragma unroll
        for (int o = 32; o; o >>= 1) d += __shfl_xor(d, o);
        if (i < CAP) st_row(i, xv);
        if (lane == 0) zs[i] = d;
    }
    __syncthreads();
    // Phase B: finish c_g, apply leaky during max pass
    float cg = red[8] + red[9] + red[10] + red[11] + blv;
    float mx = -3.4e38f;
    for (int k = tid; k < cnt; k += 256){
        float t = cg + zs[k];
        t = t >= 0.f ? t : 0.01f * t;
        zs[k] = t;
        mx = fmaxf(mx, t);
    }
    #pragma unroll
    for (int o = 32; o; o >>= 1) mx = fmaxf(mx, __shfl_xor(mx, o));
    if (lane == 0) red[wave] = mx;
    __syncthreads();
    mx = fmaxf(fmaxf(red[0], red[1]), fmaxf(red[2], red[3]));
    float dsum = 0.f;
    for (int k = tid; k < cnt; k += 256){
        float e = expf(zs[k] - mx);
        zs[k] = e;
        dsum += e;
    }
    #pragma unroll
    for (int o = 32; o; o >>= 1) dsum += __shfl_xor(dsum, o);
    if (lane == 0) red[4 + wave] = dsum;
    __syncthreads();
    float inv = 1.f / (red[4] + red[5] + red[6] + red[7]);
    // Phase C: weighted sum; thread = feature
    float acc = 0.f;
    int lim = cnt < CAP ? cnt : CAP;
    for (int k = 0; k < lim; k++) acc += zs[k] * bf16_to_f(xs[k][tid]);
    for (int k = CAP; k < cnt; k++) acc += zs[k] * x[(size_t)(s0 + k) * FF + tid];
    s_b[(size_t)g * FF + tid] = rne_bf16(acc * inv);
}

// K2: fused proj+GRU. Block = 16 graphs (one MFMA M-tile), 512 threads = 8 waves,
// wave w owns f-slice [w*32, w*32+32). Proj -> ctx tile in LDS (row pad +8 u16
// breaks the 16-way bank conflict a 256-stride would cause on ds_read_b128),
// then 6-GEMM GRU + cell epilogue. Kills the ctx_b HBM round-trip + one launch.
#define CPAD 264
__global__ __launch_bounds__(512) void k_proj_gru(
        const u16* __restrict__ s_b, const u16* __restrict__ Wp_b,
        const float* __restrict__ bp, const int* __restrict__ start,
        const u16* __restrict__ gfe_b, const u16* __restrict__ Wih_b,
        const u16* __restrict__ Whh_b, const float* __restrict__ bih,
        const float* __restrict__ bhh, const float* __restrict__ gfe,
        float* __restrict__ out){
    __shared__ __align__(16) u16 ctx_s[16][CPAD];   // 8.25 KB
    int tid = threadIdx.x;
    int w = tid >> 6, l = tid & 63;
    int mn = l & 15, q = l >> 4;
    int g0 = blockIdx.x * 16;
    int fb = w * 32;
    // ---- proj phase: ctx = ELU(s @ Wp^T + gate*bp) for 16 g x 32 f ----
    f32x4 acc[2] = {};
    const u16* arow = s_b + (size_t)(g0 + mn) * FF + q * 8;
    #pragma unroll
    for (int kb = 0; kb < 8; kb++){
        bf16x8 a = *(const bf16x8*)(arow + kb * 32);
        #pragma unroll
        for (int cc = 0; cc < 2; cc++){
            bf16x8 b = *(const bf16x8*)(Wp_b + (size_t)(fb + cc * 16 + mn) * FF + kb * 32 + q * 8);
            acc[cc] = __builtin_amdgcn_mfma_f32_16x16x32_bf16(a, b, acc[cc], 0, 0, 0);
        }
    }
    #pragma unroll
    for (int cc = 0; cc < 2; cc++){
        int f = fb + cc * 16 + mn;
        float bias = bp[f];
        #pragma unroll
        for (int r = 0; r < 4; r++){
            int g = g0 + q * 4 + r;
            float bs = (start[g + 1] > start[g]) ? 1.f : 0.f;
            float v = acc[cc][r] + bs * bias;
            v = v > 0.f ? v : expm1f(v);
            ctx_s[q * 4 + r][f] = rne_bf16(v);
        }
    }
    __syncthreads();
    // ---- GRU phase: 6 GEMM tiles (ctx@Wih_r/z/n from LDS, gfe@Whh_r/z/n) ----
    f32x4 ai[3][2] = {};
    f32x4 ah[3][2] = {};
    const u16* ag_row = gfe_b + (size_t)(g0 + mn) * FF + q * 8;
    #pragma unroll
    for (int kb = 0; kb < 8; kb++){
        bf16x8 a_c = *(const bf16x8*)(&ctx_s[mn][kb * 32 + q * 8]);
        bf16x8 a_g = *(const bf16x8*)(ag_row + kb * 32);
        #pragma unroll
        for (int s = 0; s < 3; s++){
            #pragma unroll
            for (int cc = 0; cc < 2; cc++){
                size_t woff = (size_t)(s * FF + fb + cc * 16 + mn) * FF + kb * 32 + q * 8;
                bf16x8 bi = *(const bf16x8*)(Wih_b + woff);
                ai[s][cc] = __builtin_amdgcn_mfma_f32_16x16x32_bf16(a_c, bi, ai[s][cc], 0, 0, 0);
                bf16x8 bh = *(const bf16x8*)(Whh_b + woff);
                ah[s][cc] = __builtin_amdgcn_mfma_f32_16x16x32_bf16(a_g, bh, ah[s][cc], 0, 0, 0);
            }
        }
    }
    #pragma unroll
    for (int cc = 0; cc < 2; cc++){
        int f = fb + cc * 16 + mn;
        float bir = bih[f], biz = bih[FF + f], bin_ = bih[2 * FF + f];
        float bhr = bhh[f], bhz = bhh[FF + f], bhn = bhh[2 * FF + f];
        #pragma unroll
        for (int r = 0; r < 4; r++){
            int g = g0 + q * 4 + r;
            float rg = 1.f / (1.f + expf(-(ai[0][cc][r] + bir + ah[0][cc][r] + bhr)));
            float zg = 1.f / (1.f + expf(-(ai[1][cc][r] + biz + ah[1][cc][r] + bhz)));
            float ng = tanhf(ai[2][cc][r] + bin_ + rg * (ah[2][cc][r] + bhn));
            float h = gfe[(size_t)g * FF + f];
            out[(size_t)g * FF + f] = (1.f - zg) * ng + zg * h;
        }
    }
}

extern "C" void kernel_launch(void* const* d_in, const int* in_sizes, int n_in,
                              void* d_out, int out_size, void* d_ws, size_t ws_size,
                              hipStream_t stream){
    const float* node = (const float*)d_in[0];
    const float* gfe  = (const float*)d_in[1];
    const int*   seg  = (const int*)d_in[2];
    const float* Wl   = (const float*)d_in[3];
    const float* bl   = (const float*)d_in[4];
    const float* Wp   = (const float*)d_in[5];
    const float* bp   = (const float*)d_in[6];
    const float* Wih  = (const float*)d_in[7];
    const float* Whh  = (const float*)d_in[8];
    const float* bih  = (const float*)d_in[9];
    const float* bhh  = (const float*)d_in[10];
    float* out = (float*)d_out;

    // Workspace carve-up (~6 MB total).
    char* p = (char*)d_ws;
    auto alloc = [&](size_t bytes)->void*{
        void* r = (void*)p; p += (bytes + 255) & ~(size_t)255; return r;
    };
    int*   start = (int*)  alloc((BB + 1) * sizeof(int));
    u16*   s_b   = (u16*)  alloc((size_t)BB * FF * sizeof(u16));
    u16*   gfe_b = (u16*)  alloc((size_t)BB * FF * sizeof(u16));
    u16*   Wp_b  = (u16*)  alloc((size_t)FF * FF * sizeof(u16));
    u16*   Wih_b = (u16*)  alloc((size_t)3 * FF * FF * sizeof(u16));
    u16*   Whh_b = (u16*)  alloc((size_t)3 * FF * FF * sizeof(u16));

    k_prep<<<(PREP_V4 + 255) / 256, 256, 0, stream>>>(gfe, Wp, Wih, Whh, seg, start,
                                                      gfe_b, Wp_b, Wih_b, Whh_b);
    k_attn<<<BB, 256, 0, stream>>>(node, Wl, bl, gfe, start, s_b);
    k_proj_gru<<<BB / 16, 512, 0, stream>>>(s_b, Wp_b, bp, start, gfe_b, Wih_b, Whh_b,
                                            bih, bhh, gfe, out);
}

// Round 3
// 337.257 us; speedup vs baseline: 1.1432x; 1.0195x over previous
//
#include <hip/hip_runtime.h>

// Problem constants (fixed by the reference).
#define NN 204800
#define BB 4096
#define FF 256
#define CAP 72   // LDS-staged rows per graph, bf16 (36 KB) -> 4 blocks/CU

typedef unsigned short u16;
typedef unsigned int u32;
typedef short bf16x8 __attribute__((ext_vector_type(8)));   // 8 bf16 (4 VGPRs)
typedef float f32x4  __attribute__((ext_vector_type(4)));   // MFMA accumulator
typedef float f4     __attribute__((ext_vector_type(4)));   // for nontemporal loads

__device__ __forceinline__ u16 rne_bf16(float f){
    union { u32 v; float f; } t; t.f = f;
    u32 lsb = (t.v >> 16) & 1u;
    t.v += 0x7fffu + lsb;
    return (u16)(t.v >> 16);
}
__device__ __forceinline__ float bf16_to_f(u16 h){
    union { u32 v; float f; } t; t.v = (u32)h << 16; return t.f;
}
__device__ __forceinline__ void cvt4(const float* __restrict__ src, u16* __restrict__ dst){
    float4 v = *(const float4*)src;
    ushort4 h;
    h.x = rne_bf16(v.x); h.y = rne_bf16(v.y);
    h.z = rne_bf16(v.z); h.w = rne_bf16(v.w);
    *(ushort4*)dst = h;
}

// Wave-level 64-ary lower_bound on sorted seg[0..NN): first idx with seg[idx] >= val.
// 3 ballot rounds for NN=204800 (span 3200 -> 50 -> 1). All 64 lanes participate.
__device__ __forceinline__ int lb64(const int* __restrict__ seg, int val, int lane){
    int lo = 0, hi = NN;
    while (lo < hi){
        int span = (hi - lo + 63) >> 6;
        int pos = lo + lane * span;
        int v = (pos < hi) ? seg[pos] : 0x7fffffff;
        unsigned long long m = __ballot(v < val);
        if (m == 0ull){ hi = lo; break; }   // seg[lo] >= val -> answer == lo
        int h = 63 - __clzll(m);
        int nlo = lo + h * span + 1;
        int nhi = lo + (h + 1) * span;
        lo = nlo;
        hi = nhi < hi ? nhi : hi;
    }
    return lo;
}

// Weight-conversion share embedded in k_attn: Wp + Wih + Whh = 458752 elems
// = 114688 ushort4 = exactly blocks 0..447 x 256 threads x 1 cvt4.
#define CVT_V4 ((FF*FF + 2*3*FF*FF) / 4)   // 114688

// K1: fused attention — ONE pass over node_feats per graph (nontemporal stream).
// Also: per-block segment bounds (64-ary search, waves 0/1), gfe->bf16 row write,
// gate[g] write, and the weight fp32->bf16 conversion (first 448 blocks).
__global__ __launch_bounds__(256) void k_attn(
        const float* __restrict__ x, const float* __restrict__ Wl,
        const float* __restrict__ bl, const float* __restrict__ gfe,
        const int* __restrict__ seg, u16* __restrict__ s_b,
        u16* __restrict__ gfe_b, float* __restrict__ gate,
        const float* __restrict__ Wp, const float* __restrict__ Wih,
        const float* __restrict__ Whh, u16* __restrict__ Wp_b,
        u16* __restrict__ Wih_b, u16* __restrict__ Whh_b){
    __shared__ __align__(16) u16 xs[CAP][FF];    // 36 KB (bf16 staged rows)
    __shared__ float zs[512];                    // raw z, then exp weights
    __shared__ float red[16];                    // [0:4) max, [4:8) denom, [8:12) c partials
    __shared__ int sbounds[2];
    int g = blockIdx.x;
    int tid = threadIdx.x, wave = tid >> 6, lane = tid & 63;

    // Phase 0a: gfe row -> bf16 + c_g partial = sum_f Wl[f]*relu(gfe[g,f])
    float gv = gfe[(size_t)g * FF + tid];
    gfe_b[(size_t)g * FF + tid] = rne_bf16(gv);
    float p = Wl[tid] * fmaxf(gv, 0.f);
    #pragma unroll
    for (int o = 32; o; o >>= 1) p += __shfl_xor(p, o);
    if (lane == 0) red[8 + wave] = p;

    // Phase 0b: embedded weight conversion (first 448 blocks, 1 cvt4/thread)
    int gid = g * 256 + tid;
    if (gid < CVT_V4){
        int j = gid * 4;
        const int n_wp = FF * FF, n_w3 = 3 * FF * FF;
        if (j < n_wp)            cvt4(Wp + j, Wp_b + j);
        else if ((j -= n_wp) < n_w3) cvt4(Wih + j, Wih_b + j);
        else                     cvt4(Whh + (j - n_w3), Whh_b + (j - n_w3));
    }

    // Phase 0c: segment bounds (waves 0 and 1 search g and g+1)
    if (wave < 2){
        int L = lb64(seg, g + wave, lane);
        if (lane == 0) sbounds[wave] = L;
    }
    float blv = bl[0];
    f4 wv = *(const f4*)(Wl + FF + lane * 4);
    __syncthreads();

    int s0 = sbounds[0], cnt = sbounds[1] - s0;
    if (tid == 0) gate[g] = cnt > 0 ? 1.f : 0.f;
    if (cnt == 0){                   // block-uniform: safe early exit
        s_b[(size_t)g * FF + tid] = 0;
        return;
    }

    auto st_row = [&](int row, const f4& v){
        ushort4 h;
        h.x = rne_bf16(v.x); h.y = rne_bf16(v.y);
        h.z = rne_bf16(v.z); h.w = rne_bf16(v.w);
        *(ushort4*)(&xs[row][lane * 4]) = h;
    };

    // Phase A: 8-deep burst (8 outstanding 1KB row loads per wave), nontemporal.
    // Wave handles the stride-4 row sequence {wave, wave+4, ...}.
    int i = wave;
    for (; i + 28 < cnt; i += 32){
        const f4* r0 = (const f4*)(x + (size_t)(s0 + i) * FF + lane * 4);
        f4 xv[8];
        #pragma unroll
        for (int u = 0; u < 8; u++) xv[u] = __builtin_nontemporal_load(r0 + u * FF);
        float d[8];
        #pragma unroll
        for (int u = 0; u < 8; u++)
            d[u] = xv[u].x * wv.x + xv[u].y * wv.y + xv[u].z * wv.z + xv[u].w * wv.w;
        #pragma unroll
        for (int o = 32; o; o >>= 1){
            #pragma unroll
            for (int u = 0; u < 8; u++) d[u] += __shfl_xor(d[u], o);
        }
        #pragma unroll
        for (int u = 0; u < 8; u++) if (i + u * 4 < CAP) st_row(i + u * 4, xv[u]);
        if (lane == 0){
            #pragma unroll
            for (int u = 0; u < 8; u++) zs[i + u * 4] = d[u];
        }
    }
    for (; i + 12 < cnt; i += 16){
        const f4* r0 = (const f4*)(x + (size_t)(s0 + i) * FF + lane * 4);
        f4 xv[4];
        #pragma unroll
        for (int u = 0; u < 4; u++) xv[u] = __builtin_nontemporal_load(r0 + u * FF);
        float d[4];
        #pragma unroll
        for (int u = 0; u < 4; u++)
            d[u] = xv[u].x * wv.x + xv[u].y * wv.y + xv[u].z * wv.z + xv[u].w * wv.w;
        #pragma unroll
        for (int o = 32; o; o >>= 1){
            #pragma unroll
            for (int u = 0; u < 4; u++) d[u] += __shfl_xor(d[u], o);
        }
        #pragma unroll
        for (int u = 0; u < 4; u++) if (i + u * 4 < CAP) st_row(i + u * 4, xv[u]);
        if (lane == 0){
            #pragma unroll
            for (int u = 0; u < 4; u++) zs[i + u * 4] = d[u];
        }
    }
    for (; i < cnt; i += 4){
        f4 xv = __builtin_nontemporal_load((const f4*)(x + (size_t)(s0 + i) * FF + lane * 4));
        float d = xv.x * wv.x + xv.y * wv.y + xv.z * wv.z + xv.w * wv.w;
        #pragma unroll
        for (int o = 32; o; o >>= 1) d += __shfl_xor(d, o);
        if (i < CAP) st_row(i, xv);
        if (lane == 0) zs[i] = d;
    }
    __syncthreads();
    // Phase B: finish c_g, apply leaky during max pass
    float cg = red[8] + red[9] + red[10] + red[11] + blv;
    float mx = -3.4e38f;
    for (int k = tid; k < cnt; k += 256){
        float t = cg + zs[k];
        t = t >= 0.f ? t : 0.01f * t;
        zs[k] = t;
        mx = fmaxf(mx, t);
    }
    #pragma unroll
    for (int o = 32; o; o >>= 1) mx = fmaxf(mx, __shfl_xor(mx, o));
    if (lane == 0) red[wave] = mx;
    __syncthreads();
    mx = fmaxf(fmaxf(red[0], red[1]), fmaxf(red[2], red[3]));
    float dsum = 0.f;
    for (int k = tid; k < cnt; k += 256){
        float e = expf(zs[k] - mx);
        zs[k] = e;
        dsum += e;
    }
    #pragma unroll
    for (int o = 32; o; o >>= 1) dsum += __shfl_xor(dsum, o);
    if (lane == 0) red[4 + wave] = dsum;
    __syncthreads();
    float inv = 1.f / (red[4] + red[5] + red[6] + red[7]);
    // Phase C: weighted sum; thread = feature
    float acc = 0.f;
    int lim = cnt < CAP ? cnt : CAP;
    for (int k = 0; k < lim; k++) acc += zs[k] * bf16_to_f(xs[k][tid]);
    for (int k = CAP; k < cnt; k++) acc += zs[k] * x[(size_t)(s0 + k) * FF + tid];
    s_b[(size_t)g * FF + tid] = rne_bf16(acc * inv);
}

// K2: fused proj+GRU. Block = 16 graphs (one MFMA M-tile), 512 threads = 8 waves,
// wave w owns f-slice [w*32, w*32+32). Proj -> ctx tile in LDS (row pad +8 u16
// breaks the 16-way bank conflict a 256-stride would cause on ds_read_b128),
// then 6-GEMM GRU + cell epilogue.
#define CPAD 264
__global__ __launch_bounds__(512) void k_proj_gru(
        const u16* __restrict__ s_b, const u16* __restrict__ Wp_b,
        const float* __restrict__ bp, const float* __restrict__ gate,
        const u16* __restrict__ gfe_b, const u16* __restrict__ Wih_b,
        const u16* __restrict__ Whh_b, const float* __restrict__ bih,
        const float* __restrict__ bhh, const float* __restrict__ gfe,
        float* __restrict__ out){
    __shared__ __align__(16) u16 ctx_s[16][CPAD];   // 8.25 KB
    int tid = threadIdx.x;
    int w = tid >> 6, l = tid & 63;
    int mn = l & 15, q = l >> 4;
    int g0 = blockIdx.x * 16;
    int fb = w * 32;
    // ---- proj phase: ctx = ELU(s @ Wp^T + gate*bp) for 16 g x 32 f ----
    f32x4 acc[2] = {};
    const u16* arow = s_b + (size_t)(g0 + mn) * FF + q * 8;
    #pragma unroll
    for (int kb = 0; kb < 8; kb++){
        bf16x8 a = *(const bf16x8*)(arow + kb * 32);
        #pragma unroll
        for (int cc = 0; cc < 2; cc++){
            bf16x8 b = *(const bf16x8*)(Wp_b + (size_t)(fb + cc * 16 + mn) * FF + kb * 32 + q * 8);
            acc[cc] = __builtin_amdgcn_mfma_f32_16x16x32_bf16(a, b, acc[cc], 0, 0, 0);
        }
    }
    #pragma unroll
    for (int cc = 0; cc < 2; cc++){
        int f = fb + cc * 16 + mn;
        float bias = bp[f];
        #pragma unroll
        for (int r = 0; r < 4; r++){
            int g = g0 + q * 4 + r;
            float v = acc[cc][r] + gate[g] * bias;
            v = v > 0.f ? v : expm1f(v);
            ctx_s[q * 4 + r][f] = rne_bf16(v);
        }
    }
    __syncthreads();
    // ---- GRU phase: 6 GEMM tiles (ctx@Wih_r/z/n from LDS, gfe@Whh_r/z/n) ----
    f32x4 ai[3][2] = {};
    f32x4 ah[3][2] = {};
    const u16* ag_row = gfe_b + (size_t)(g0 + mn) * FF + q * 8;
    #pragma unroll
    for (int kb = 0; kb < 8; kb++){
        bf16x8 a_c = *(const bf16x8*)(&ctx_s[mn][kb * 32 + q * 8]);
        bf16x8 a_g = *(const bf16x8*)(ag_row + kb * 32);
        #pragma unroll
        for (int s = 0; s < 3; s++){
            #pragma unroll
            for (int cc = 0; cc < 2; cc++){
                size_t woff = (size_t)(s * FF + fb + cc * 16 + mn) * FF + kb * 32 + q * 8;
                bf16x8 bi = *(const bf16x8*)(Wih_b + woff);
                ai[s][cc] = __builtin_amdgcn_mfma_f32_16x16x32_bf16(a_c, bi, ai[s][cc], 0, 0, 0);
                bf16x8 bh = *(const bf16x8*)(Whh_b + woff);
                ah[s][cc] = __builtin_amdgcn_mfma_f32_16x16x32_bf16(a_g, bh, ah[s][cc], 0, 0, 0);
            }
        }
    }
    #pragma unroll
    for (int cc = 0; cc < 2; cc++){
        int f = fb + cc * 16 + mn;
        float bir = bih[f], biz = bih[FF + f], bin_ = bih[2 * FF + f];
        float bhr = bhh[f], bhz = bhh[FF + f], bhn = bhh[2 * FF + f];
        #pragma unroll
        for (int r = 0; r < 4; r++){
            int g = g0 + q * 4 + r;
            float rg = 1.f / (1.f + expf(-(ai[0][cc][r] + bir + ah[0][cc][r] + bhr)));
            float zg = 1.f / (1.f + expf(-(ai[1][cc][r] + biz + ah[1][cc][r] + bhz)));
            float ng = tanhf(ai[2][cc][r] + bin_ + rg * (ah[2][cc][r] + bhn));
            float h = gfe[(size_t)g * FF + f];
            out[(size_t)g * FF + f] = (1.f - zg) * ng + zg * h;
        }
    }
}

extern "C" void kernel_launch(void* const* d_in, const int* in_sizes, int n_in,
                              void* d_out, int out_size, void* d_ws, size_t ws_size,
                              hipStream_t stream){
    const float* node = (const float*)d_in[0];
    const float* gfe  = (const float*)d_in[1];
    const int*   seg  = (const int*)d_in[2];
    const float* Wl   = (const float*)d_in[3];
    const float* bl   = (const float*)d_in[4];
    const float* Wp   = (const float*)d_in[5];
    const float* bp   = (const float*)d_in[6];
    const float* Wih  = (const float*)d_in[7];
    const float* Whh  = (const float*)d_in[8];
    const float* bih  = (const float*)d_in[9];
    const float* bhh  = (const float*)d_in[10];
    float* out = (float*)d_out;

    // Workspace carve-up (~6 MB total).
    char* p = (char*)d_ws;
    auto alloc = [&](size_t bytes)->void*{
        void* r = (void*)p; p += (bytes + 255) & ~(size_t)255; return r;
    };
    float* gate  = (float*)alloc(BB * sizeof(float));
    u16*   s_b   = (u16*)  alloc((size_t)BB * FF * sizeof(u16));
    u16*   gfe_b = (u16*)  alloc((size_t)BB * FF * sizeof(u16));
    u16*   Wp_b  = (u16*)  alloc((size_t)FF * FF * sizeof(u16));
    u16*   Wih_b = (u16*)  alloc((size_t)3 * FF * FF * sizeof(u16));
    u16*   Whh_b = (u16*)  alloc((size_t)3 * FF * FF * sizeof(u16));

    k_attn<<<BB, 256, 0, stream>>>(node, Wl, bl, gfe, seg, s_b, gfe_b, gate,
                                   Wp, Wih, Whh, Wp_b, Wih_b, Whh_b);
    k_proj_gru<<<BB / 16, 512, 0, stream>>>(s_b, Wp_b, bp, gate, gfe_b, Wih_b, Whh_b,
                                            bih, bhh, gfe, out);
}